// Round 4
// baseline (14470.624 us; speedup 1.0000x reference)
//
#include <hip/hip_runtime.h>

#define EMBD 256
#define HIDD 512
#define SEQL 512
#define KTOT 768
#define KP   384          // h2-packed dwords per input row
#define NCOL 512
#define RG_ROWS 4
#define NRG  32           // row groups
#define NCG  8            // col groups (WGs per row group)
#define CGC  64           // cols per WG
#define NWG  (NRG * NCG)  // 256
#define THR  512

typedef unsigned int u32;
typedef unsigned long long u64;
typedef _Float16 h2 __attribute__((ext_vector_type(2)));

#define WS_W16_OFF  0
#define WS_FLG_OFF  (768 * 1024)               // 256 flags, 64 B apart (16 KB)
#define WS_X_OFF    (768 * 1024 + 16384)       // X[2][NRG][1024 dwords]

static __device__ __forceinline__ float dot2(u32 a, u32 b, float c) {
#if __has_builtin(__builtin_amdgcn_fdot2)
    return __builtin_amdgcn_fdot2(__builtin_bit_cast(h2, a), __builtin_bit_cast(h2, b), c, false);
#else
    h2 ha = __builtin_bit_cast(h2, a), hb = __builtin_bit_cast(h2, b);
    float r = fmaf((float)ha.x, (float)hb.x, c);
    return fmaf((float)ha.y, (float)hb.y, r);
#endif
}

static __device__ __forceinline__ u32 packh2(float a, float b) {
    _Float16 lo = (_Float16)a, hi = (_Float16)b;
    return (u32)__builtin_bit_cast(unsigned short, lo)
         | ((u32)__builtin_bit_cast(unsigned short, hi) << 16);
}

__global__ __launch_bounds__(1024)
void init_flags(u32* __restrict__ flg) {
    for (int i = threadIdx.x; i < 4096; i += 1024) flg[i] = 0u;
}

// W (f32 [768][512]) -> W16 (dword [384][512]): dword(kp,c) = (h(W[2kp][c]), h(W[2kp+1][c]))
__global__ __launch_bounds__(256)
void convert_W(const float* __restrict__ W, u32* __restrict__ W16) {
    int idx = blockIdx.x * 256 + threadIdx.x;
    if (idx >= KP * NCOL) return;
    int kp = idx >> 9, c = idx & 511;
    float lo = W[(size_t)(2 * kp) * NCOL + c];
    float hi = W[(size_t)(2 * kp + 1) * NCOL + c];
    W16[idx] = packh2(lo, hi);
}

// 256 WGs x 512 threads. WG (rg,cg): rows rg*4..+3, cols cg*64..+63.
// Thread: ks = tid>>6 (48 k-pairs), lane = tid&63 (1 col). W slice in 48 VGPRs.
// Exchange: per-(rg,cg) epoch flags; loader threads poll only their source flag.
__global__ __launch_bounds__(THR, 1)
void rnn_coop2(const int*   __restrict__ tokens,
               const float* __restrict__ V,
               const u32*   __restrict__ W16,
               const float* __restrict__ bias,
               const float* __restrict__ Wd,
               const float* __restrict__ bd,
               float*       __restrict__ y,
               u32*         __restrict__ flg,
               u32*         __restrict__ X)
{
    __shared__ __align__(16) u32 vcur[RG_ROWS][KP];      // [0..127]=emb, [128..383]=state
    __shared__ float part[RG_ROWS][CGC][9];
    __shared__ int   toks[RG_ROWS][SEQL];
    __shared__ float yred[8];

    const int tid  = threadIdx.x;
    const int wg   = blockIdx.x;
    const int rg   = wg >> 3;
    const int cg   = wg & 7;
    const int ks   = tid >> 6;           // 0..7
    const int lane = tid & 63;
    const int gc   = cg * CGC + lane;
    const int row0 = rg * RG_ROWS;

    for (int i = tid; i < RG_ROWS * SEQL; i += THR)
        toks[i >> 9][i & 511] = tokens[(row0 + (i >> 9)) * SEQL + (i & 511)];
    for (int i = tid; i < RG_ROWS * 256; i += THR)
        vcur[i >> 8][128 + (i & 255)] = 0u;

    u32 w[48];
    #pragma unroll
    for (int i = 0; i < 48; ++i)
        w[i] = W16[(size_t)(ks * 48 + i) * NCOL + gc];

    __syncthreads();

    // emb(0): thread -> (row er, pair ee)
    const int er = tid >> 7, ee = tid & 127;
    {
        int tok = toks[er][0];
        float2 ev = *(const float2*)&V[(size_t)tok * EMBD + 2 * ee];
        vcur[er][ee] = packh2(ev.x, ev.y);
    }
    __syncthreads();

    const float bias_r = (tid < 256) ? bias[cg * CGC + (tid & 63)] : 0.f;

    // exchange-loader role: u64 index tid -> dwords (2tid, 2tid+1)
    const int src = (tid >> 4) & 7;      // source col-group of my u64
    const int lr  = tid >> 7;            // row
    const int lcp = (2 * tid) & 255;     // dword within row
    u32* const myflag  = flg + (rg * NCG + cg)  * 16;
    u32* const srcflag = flg + (rg * NCG + src) * 16;

    for (int t = 0; t < SEQL; ++t) {
        // ---- exchange-in: state(t-1) from peers ----
        if (t > 0 && src != cg) {
            const u32 tv = (u32)t;
            while (__hip_atomic_load(srcflag, __ATOMIC_ACQUIRE, __HIP_MEMORY_SCOPE_AGENT) < tv)
                __builtin_amdgcn_s_sleep(1);
            const u64* Xr = (const u64*)(X + ((size_t)((t - 1) & 1) * NRG + rg) * 1024);
            u64 two = __hip_atomic_load(Xr + tid, __ATOMIC_RELAXED, __HIP_MEMORY_SCOPE_AGENT);
            *(u64*)&vcur[lr][128 + lcp] = two;
        }
        __syncthreads();   // B0: state(t-1) + emb(t) fully in vcur

        // emb(t+1) prefetch (latency hidden under matvec)
        int tn   = (t + 1 < SEQL) ? (t + 1) : (SEQL - 1);
        int tokn = toks[er][tn];
        float2 ev = *(const float2*)&V[(size_t)tokn * EMBD + 2 * ee];

        // ---- matvec over our 48 k-pairs, col gc, 4 rows ----
        float acc0 = 0.f, acc1 = 0.f, acc2 = 0.f, acc3 = 0.f;
        const uint4* vb = (const uint4*)vcur;   // [4][96]
        const int kb = ks * 12;
        #pragma unroll
        for (int j = 0; j < 12; ++j) {
            uint4 a0 = vb[0 * 96 + kb + j];     // wave-uniform broadcast reads
            uint4 a1 = vb[1 * 96 + kb + j];
            uint4 a2 = vb[2 * 96 + kb + j];
            uint4 a3 = vb[3 * 96 + kb + j];
            acc0 = dot2(a0.x, w[4*j+0], acc0); acc0 = dot2(a0.y, w[4*j+1], acc0);
            acc0 = dot2(a0.z, w[4*j+2], acc0); acc0 = dot2(a0.w, w[4*j+3], acc0);
            acc1 = dot2(a1.x, w[4*j+0], acc1); acc1 = dot2(a1.y, w[4*j+1], acc1);
            acc1 = dot2(a1.z, w[4*j+2], acc1); acc1 = dot2(a1.w, w[4*j+3], acc1);
            acc2 = dot2(a2.x, w[4*j+0], acc2); acc2 = dot2(a2.y, w[4*j+1], acc2);
            acc2 = dot2(a2.z, w[4*j+2], acc2); acc2 = dot2(a2.w, w[4*j+3], acc2);
            acc3 = dot2(a3.x, w[4*j+0], acc3); acc3 = dot2(a3.y, w[4*j+1], acc3);
            acc3 = dot2(a3.z, w[4*j+2], acc3); acc3 = dot2(a3.w, w[4*j+3], acc3);
        }
        part[0][lane][ks] = acc0;
        part[1][lane][ks] = acc1;
        part[2][lane][ks] = acc2;
        part[3][lane][ks] = acc3;
        __syncthreads();   // B1: partials visible, vcur reads done

        // ---- reduce + tanh + publish; emb(t+1) -> vcur ----
        if (tid < 256) {
            const int rr = tid >> 6, rc = tid & 63;
            float s = part[rr][rc][0] + part[rr][rc][1] + part[rr][rc][2] + part[rr][rc][3]
                    + part[rr][rc][4] + part[rr][rc][5] + part[rr][rc][6] + part[rr][rc][7]
                    + bias_r;
            s = tanhf(s);
            float snb = __shfl_down(s, 1);
            if ((rc & 1) == 0) {
                u32 dw = packh2(s, snb);
                const int cpi = cg * 32 + (rc >> 1);
                vcur[rr][128 + cpi] = dw;   // own slice straight to LDS
                u32* p = X + ((size_t)(t & 1) * NRG + rg) * 1024 + rr * 256 + cpi;
                __hip_atomic_store(p, dw, __ATOMIC_RELAXED, __HIP_MEMORY_SCOPE_AGENT);
            }
        }
        vcur[er][ee] = packh2(ev.x, ev.y);
        __syncthreads();   // B2: drains vmcnt -> X stores globally visible
        if (tid == 0)
            __hip_atomic_store(myflag, (u32)(t + 1), __ATOMIC_RELEASE, __HIP_MEMORY_SCOPE_AGENT);
    }

    // ---- epilogue: cg==0 WGs gather state(511) and compute y ----
    if (cg == 0) {
        if (src != 0) {
            while (__hip_atomic_load(srcflag, __ATOMIC_ACQUIRE, __HIP_MEMORY_SCOPE_AGENT) < (u32)SEQL)
                __builtin_amdgcn_s_sleep(1);
            const u64* Xr = (const u64*)(X + ((size_t)((SEQL - 1) & 1) * NRG + rg) * 1024);
            u64 two = __hip_atomic_load(Xr + tid, __ATOMIC_RELAXED, __HIP_MEMORY_SCOPE_AGENT);
            *(u64*)&vcur[lr][128 + lcp] = two;
        }
        __syncthreads();
        const int r = tid >> 7, q = tid & 127;
        u32 dA = vcur[r][128 + 2 * q], dB = vcur[r][128 + 2 * q + 1];
        h2 a = __builtin_bit_cast(h2, dA), b = __builtin_bit_cast(h2, dB);
        float p = (float)a.x * Wd[4 * q + 0] + (float)a.y * Wd[4 * q + 1]
                + (float)b.x * Wd[4 * q + 2] + (float)b.y * Wd[4 * q + 3];
        #pragma unroll
        for (int off = 32; off > 0; off >>= 1) p += __shfl_down(p, off);
        if ((tid & 63) == 0) yred[tid >> 6] = p;
        __syncthreads();
        if (tid < 4) y[row0 + tid] = yred[2 * tid] + yred[2 * tid + 1] + bd[0];
    }
}

extern "C" void kernel_launch(void* const* d_in, const int* in_sizes, int n_in,
                              void* d_out, int out_size, void* d_ws, size_t ws_size,
                              hipStream_t stream)
{
    const int*   tokens = (const int*)  d_in[0];
    const float* V      = (const float*)d_in[1];
    const float* W      = (const float*)d_in[2];
    const float* b      = (const float*)d_in[3];
    const float* Wd     = (const float*)d_in[4];
    const float* bd     = (const float*)d_in[5];
    float* y = (float*)d_out;

    u32* W16 = (u32*)((char*)d_ws + WS_W16_OFF);
    u32* flg = (u32*)((char*)d_ws + WS_FLG_OFF);
    u32* X   = (u32*)((char*)d_ws + WS_X_OFF);

    hipLaunchKernelGGL(init_flags, dim3(1), dim3(1024), 0, stream, flg);
    hipLaunchKernelGGL(convert_W, dim3((KP * NCOL + 255) / 256), dim3(256), 0, stream, W, W16);
    hipLaunchKernelGGL(rnn_coop2, dim3(NWG), dim3(THR), 0, stream,
                       tokens, V, W16, b, Wd, bd, y, flg, X);
}

// Round 5
// 3094.624 us; speedup vs baseline: 4.6761x; 4.6761x over previous
//
#include <hip/hip_runtime.h>

#define EMBD 256
#define HIDD 512
#define SEQL 512
#define KP   384          // h2-packed dwords per input row (768 k / 2)
#define NCOL 512
#define RG_ROWS 4
#define NRG  32           // row groups
#define NCG  8            // col groups (WGs per row group)
#define CGC  64           // cols per WG
#define NWG  (NRG * NCG)  // 256
#define THR  512

typedef unsigned int u32;
typedef unsigned long long u64;
typedef _Float16 h2 __attribute__((ext_vector_type(2)));

#define WS_W16_OFF  0
#define WS_FLG_OFF  (768 * 1024)               // 256 flags, 128 B apart (32 KB)
#define WS_X_OFF    (768 * 1024 + 32768)       // X[2][NRG][1024 dwords]

static __device__ __forceinline__ float dot2(u32 a, u32 b, float c) {
#if __has_builtin(__builtin_amdgcn_fdot2)
    return __builtin_amdgcn_fdot2(__builtin_bit_cast(h2, a), __builtin_bit_cast(h2, b), c, false);
#else
    h2 ha = __builtin_bit_cast(h2, a), hb = __builtin_bit_cast(h2, b);
    float r = fmaf((float)ha.x, (float)hb.x, c);
    return fmaf((float)ha.y, (float)hb.y, r);
#endif
}

static __device__ __forceinline__ u32 packh2(float a, float b) {
    _Float16 lo = (_Float16)a, hi = (_Float16)b;
    return (u32)__builtin_bit_cast(unsigned short, lo)
         | ((u32)__builtin_bit_cast(unsigned short, hi) << 16);
}

__global__ __launch_bounds__(1024)
void init_flags(u32* __restrict__ flg) {
    for (int i = threadIdx.x; i < 8192; i += 1024) flg[i] = 0u;
}

// W (f32 [768][512]) -> W16 (dword [384][512]): dword(kp,c) = (h(W[2kp][c]), h(W[2kp+1][c]))
__global__ __launch_bounds__(256)
void convert_W(const float* __restrict__ W, u32* __restrict__ W16) {
    int idx = blockIdx.x * 256 + threadIdx.x;
    if (idx >= KP * NCOL) return;
    int kp = idx >> 9, c = idx & 511;
    float lo = W[(size_t)(2 * kp) * NCOL + c];
    float hi = W[(size_t)(2 * kp + 1) * NCOL + c];
    W16[idx] = packh2(lo, hi);
}

// 256 WGs x 512 threads. WG (rg,cg): rows rg*4..+3, cols cg*64..+63.
// Wave wv (0..7) = k-slice AND source col-group: emb pairs [wv*16,+16),
// state pairs [wv*32,+32) == output slice of WG (rg,wv). lane = col (0..63).
// Exchange is per-wave: lane0 relaxed-polls flag[wv], wave loads slice, ds_writes,
// computes. Own slice (wv==cg) arrives via LDS from the reduce phase.
__global__ __launch_bounds__(THR, 1)
void rnn_coop3(const int*   __restrict__ tokens,
               const float* __restrict__ V,
               const u32*   __restrict__ W16,
               const float* __restrict__ bias,
               const float* __restrict__ Wd,
               const float* __restrict__ bd,
               float*       __restrict__ y,
               u32*         __restrict__ flg,
               u32*         __restrict__ X)
{
    __shared__ __align__(16) u32 vcur[RG_ROWS][KP];      // [0..127]=emb pairs, [128..383]=state pairs
    __shared__ float part[RG_ROWS][CGC][9];
    __shared__ int   toks[RG_ROWS][SEQL];
    __shared__ float yred[8];

    const int tid  = threadIdx.x;
    const int wg   = blockIdx.x;
    const int rg   = wg >> 3;
    const int cg   = wg & 7;
    const int wv   = tid >> 6;           // wave id = k-slice = source cg
    const int lane = tid & 63;           // col within our 64
    const int gc   = cg * CGC + lane;
    const int row0 = rg * RG_ROWS;

    for (int i = tid; i < RG_ROWS * SEQL; i += THR)
        toks[i >> 9][i & 511] = tokens[(row0 + (i >> 9)) * SEQL + (i & 511)];
    for (int i = tid; i < RG_ROWS * 256; i += THR)
        vcur[i >> 8][128 + (i & 255)] = 0u;

    // W slices in registers: emb 16 + state 32 dwords
    u32 we[16], ws[32];
    #pragma unroll
    for (int i = 0; i < 16; ++i)
        we[i] = W16[(size_t)(wv * 16 + i) * NCOL + gc];
    #pragma unroll
    for (int j = 0; j < 32; ++j)
        ws[j] = W16[(size_t)(128 + wv * 32 + j) * NCOL + gc];

    __syncthreads();

    // emb(0): thread -> (row er, pair ee)
    const int er = tid >> 7, ee = tid & 127;
    {
        int tok = toks[er][0];
        float2 ev = *(const float2*)&V[(size_t)tok * EMBD + 2 * ee];
        vcur[er][ee] = packh2(ev.x, ev.y);
    }
    __syncthreads();

    const float bias_r = (tid < 256) ? bias[cg * CGC + (tid & 63)] : 0.f;

    // loader mapping within wave: lane -> (row lr, u64 slot lj)
    const int lr = lane >> 4, lj = lane & 15;
    u32* const myflag  = flg + (rg * NCG + cg) * 32;
    u32* const srcflag = flg + (rg * NCG + wv) * 32;

    for (int t = 0; t < SEQL; ++t) {
        // ---- phase E: emb-part matvec (emb(t) available since last B2) ----
        float a0 = 0.f, a1 = 0.f, a2 = 0.f, a3 = 0.f;
        {
            const uint4* v0 = (const uint4*)&vcur[0][wv * 16];
            const uint4* v1 = (const uint4*)&vcur[1][wv * 16];
            const uint4* v2 = (const uint4*)&vcur[2][wv * 16];
            const uint4* v3 = (const uint4*)&vcur[3][wv * 16];
            #pragma unroll
            for (int j = 0; j < 4; ++j) {
                uint4 b0 = v0[j], b1 = v1[j], b2 = v2[j], b3 = v3[j];
                a0 = dot2(b0.x, we[4*j+0], a0); a0 = dot2(b0.y, we[4*j+1], a0);
                a0 = dot2(b0.z, we[4*j+2], a0); a0 = dot2(b0.w, we[4*j+3], a0);
                a1 = dot2(b1.x, we[4*j+0], a1); a1 = dot2(b1.y, we[4*j+1], a1);
                a1 = dot2(b1.z, we[4*j+2], a1); a1 = dot2(b1.w, we[4*j+3], a1);
                a2 = dot2(b2.x, we[4*j+0], a2); a2 = dot2(b2.y, we[4*j+1], a2);
                a2 = dot2(b2.z, we[4*j+2], a2); a2 = dot2(b2.w, we[4*j+3], a2);
                a3 = dot2(b3.x, we[4*j+0], a3); a3 = dot2(b3.y, we[4*j+1], a3);
                a3 = dot2(b3.z, we[4*j+2], a3); a3 = dot2(b3.w, we[4*j+3], a3);
            }
        }

        // emb(t+1) prefetch
        int tn   = (t + 1 < SEQL) ? (t + 1) : (SEQL - 1);
        int tokn = toks[er][tn];
        float2 ev = *(const float2*)&V[(size_t)tokn * EMBD + 2 * ee];

        // ---- per-wave exchange-in: slice wv of state(t-1) ----
        if (t > 0 && wv != cg) {
            if (lane == 0) {
                while (__hip_atomic_load(srcflag, __ATOMIC_RELAXED, __HIP_MEMORY_SCOPE_AGENT) < (u32)t) { }
            }
            asm volatile("" ::: "memory");   // no hoisting of data loads above poll
            const u64* Xr = (const u64*)(X + ((size_t)((t - 1) & 1) * NRG + rg) * 1024);
            u64 two = __hip_atomic_load(Xr + lr * 128 + wv * 16 + lj,
                                        __ATOMIC_RELAXED, __HIP_MEMORY_SCOPE_AGENT);
            *(u64*)&vcur[lr][128 + wv * 32 + 2 * lj] = two;
        }

        // ---- phase S: state-part matvec over our 32 pairs ----
        {
            const uint4* v0 = (const uint4*)&vcur[0][128 + wv * 32];
            const uint4* v1 = (const uint4*)&vcur[1][128 + wv * 32];
            const uint4* v2 = (const uint4*)&vcur[2][128 + wv * 32];
            const uint4* v3 = (const uint4*)&vcur[3][128 + wv * 32];
            #pragma unroll
            for (int j = 0; j < 8; ++j) {
                uint4 b0 = v0[j], b1 = v1[j], b2 = v2[j], b3 = v3[j];
                a0 = dot2(b0.x, ws[4*j+0], a0); a0 = dot2(b0.y, ws[4*j+1], a0);
                a0 = dot2(b0.z, ws[4*j+2], a0); a0 = dot2(b0.w, ws[4*j+3], a0);
                a1 = dot2(b1.x, ws[4*j+0], a1); a1 = dot2(b1.y, ws[4*j+1], a1);
                a1 = dot2(b1.z, ws[4*j+2], a1); a1 = dot2(b1.w, ws[4*j+3], a1);
                a2 = dot2(b2.x, ws[4*j+0], a2); a2 = dot2(b2.y, ws[4*j+1], a2);
                a2 = dot2(b2.z, ws[4*j+2], a2); a2 = dot2(b2.w, ws[4*j+3], a2);
                a3 = dot2(b3.x, ws[4*j+0], a3); a3 = dot2(b3.y, ws[4*j+1], a3);
                a3 = dot2(b3.z, ws[4*j+2], a3); a3 = dot2(b3.w, ws[4*j+3], a3);
            }
        }
        part[0][lane][wv] = a0;
        part[1][lane][wv] = a1;
        part[2][lane][wv] = a2;
        part[3][lane][wv] = a3;
        __syncthreads();   // B1: partials visible; all vcur reads done

        // ---- reduce + tanh + publish; emb(t+1) -> vcur ----
        if (tid < 256) {
            const int rr = tid >> 6, rc = tid & 63;
            float s = part[rr][rc][0] + part[rr][rc][1] + part[rr][rc][2] + part[rr][rc][3]
                    + part[rr][rc][4] + part[rr][rc][5] + part[rr][rc][6] + part[rr][rc][7]
                    + bias_r;
            s = tanhf(s);
            float snb = __shfl_down(s, 1);
            if ((rc & 1) == 0) {
                u32 dw = packh2(s, snb);
                const int cpi = cg * 32 + (rc >> 1);
                vcur[rr][128 + cpi] = dw;   // own slice straight to LDS
                u32* p = X + ((size_t)(t & 1) * NRG + rg) * 1024 + rr * 256 + cpi;
                __hip_atomic_store(p, dw, __ATOMIC_RELAXED, __HIP_MEMORY_SCOPE_AGENT);
            }
        }
        vcur[er][ee] = packh2(ev.x, ev.y);
        __syncthreads();   // B2: drains vmcnt -> X stores visible at coherence point
        if (tid == 0)
            __hip_atomic_store(myflag, (u32)(t + 1), __ATOMIC_RELEASE, __HIP_MEMORY_SCOPE_AGENT);
    }

    // ---- epilogue: cg==0 WGs gather state(511) and compute y ----
    if (cg == 0) {
        if (wv != 0) {
            if (lane == 0) {
                while (__hip_atomic_load(srcflag, __ATOMIC_RELAXED, __HIP_MEMORY_SCOPE_AGENT) < (u32)SEQL) { }
            }
            asm volatile("" ::: "memory");
            const u64* Xr = (const u64*)(X + ((size_t)((SEQL - 1) & 1) * NRG + rg) * 1024);
            u64 two = __hip_atomic_load(Xr + lr * 128 + wv * 16 + lj,
                                        __ATOMIC_RELAXED, __HIP_MEMORY_SCOPE_AGENT);
            *(u64*)&vcur[lr][128 + wv * 32 + 2 * lj] = two;
        }
        __syncthreads();
        const int r = tid >> 7, q = tid & 127;
        u32 dA = vcur[r][128 + 2 * q], dB = vcur[r][128 + 2 * q + 1];
        h2 a = __builtin_bit_cast(h2, dA), b = __builtin_bit_cast(h2, dB);
        float p = (float)a.x * Wd[4 * q + 0] + (float)a.y * Wd[4 * q + 1]
                + (float)b.x * Wd[4 * q + 2] + (float)b.y * Wd[4 * q + 3];
        #pragma unroll
        for (int off = 32; off > 0; off >>= 1) p += __shfl_down(p, off);
        if ((tid & 63) == 0) yred[tid >> 6] = p;
        __syncthreads();
        if (tid < 4) y[row0 + tid] = yred[2 * tid] + yred[2 * tid + 1] + bd[0];
    }
}

extern "C" void kernel_launch(void* const* d_in, const int* in_sizes, int n_in,
                              void* d_out, int out_size, void* d_ws, size_t ws_size,
                              hipStream_t stream)
{
    const int*   tokens = (const int*)  d_in[0];
    const float* V      = (const float*)d_in[1];
    const float* W      = (const float*)d_in[2];
    const float* b      = (const float*)d_in[3];
    const float* Wd     = (const float*)d_in[4];
    const float* bd     = (const float*)d_in[5];
    float* y = (float*)d_out;

    u32* W16 = (u32*)((char*)d_ws + WS_W16_OFF);
    u32* flg = (u32*)((char*)d_ws + WS_FLG_OFF);
    u32* X   = (u32*)((char*)d_ws + WS_X_OFF);

    hipLaunchKernelGGL(init_flags, dim3(1), dim3(1024), 0, stream, flg);
    hipLaunchKernelGGL(convert_W, dim3((KP * NCOL + 255) / 256), dim3(256), 0, stream, W, W16);
    hipLaunchKernelGGL(rnn_coop3, dim3(NWG), dim3(THR), 0, stream,
                       tokens, V, W16, b, Wd, bd, y, flg, X);
}

// Round 6
// 1089.181 us; speedup vs baseline: 13.2858x; 2.8412x over previous
//
#include <hip/hip_runtime.h>

#define EMBD 256
#define HIDD 512
#define SEQL 512
#define NCOL 512
#define CGC  64
#define THR  512
#define NRING 64          // rings of 2 batch rows; 8 WGs (col-groups) per ring
#define RPW  2            // rows per ring

typedef unsigned int u32;
typedef unsigned long long u64;
typedef _Float16 h2 __attribute__((ext_vector_type(2)));

#define WS_W16_OFF 0
#define WS_X_OFF   (768 * 1024)
// X: u64[2 slots][NRING][RPW][256 pairs] = 512 KB. Each u64 = (tag32<<32)|(2 f16 cols)

static __device__ __forceinline__ float dot2(u32 a, u32 b, float c) {
#if __has_builtin(__builtin_amdgcn_fdot2)
    return __builtin_amdgcn_fdot2(__builtin_bit_cast(h2, a), __builtin_bit_cast(h2, b), c, false);
#else
    h2 ha = __builtin_bit_cast(h2, a), hb = __builtin_bit_cast(h2, b);
    float r = fmaf((float)ha.x, (float)hb.x, c);
    return fmaf((float)ha.y, (float)hb.y, r);
#endif
}

static __device__ __forceinline__ u32 packh2(float a, float b) {
    _Float16 lo = (_Float16)a, hi = (_Float16)b;
    return (u32)__builtin_bit_cast(unsigned short, lo)
         | ((u32)__builtin_bit_cast(unsigned short, hi) << 16);
}

// zero both X slots (65536 u64) -- clears stale tags from previous graph replays
__global__ __launch_bounds__(1024)
void init_X(u64* __restrict__ X) {
    X[(size_t)blockIdx.x * 1024 + threadIdx.x] = 0ull;
}

// W (f32 [768][512]) -> W16 (dword [384][512]): dword(kp,c) = (h(W[2kp][c]), h(W[2kp+1][c]))
__global__ __launch_bounds__(256)
void convert_W(const float* __restrict__ W, u32* __restrict__ W16) {
    int idx = blockIdx.x * 256 + threadIdx.x;
    if (idx >= 384 * NCOL) return;
    int kp = idx >> 9, c = idx & 511;
    float lo = W[(size_t)(2 * kp) * NCOL + c];
    float hi = W[(size_t)(2 * kp + 1) * NCOL + c];
    W16[idx] = packh2(lo, hi);
}

// 256 WGs x 512 thr. WG (pr, cg): rings 2pr, 2pr+1 (rows pr*4..+3), cols [cg*64,+64).
// Wave wv = k-slice: emb pairs [wv*16,+16), state pairs [wv*32,+32) = producer cg'=wv.
// Exchange: speculative tag-validated u64 loads; own slice (wv==cg) via LDS.
__global__ __launch_bounds__(THR, 1)
void rnn_ring(const int*   __restrict__ tokens,
              const float* __restrict__ V,
              const u32*   __restrict__ W16,
              const float* __restrict__ bias,
              const float* __restrict__ Wd,
              const float* __restrict__ bd,
              float*       __restrict__ y,
              u64*         __restrict__ X)
{
    __shared__ __align__(16) u32 vcA[RPW][384];   // [0..127]=emb pairs, [128..383]=state pairs
    __shared__ __align__(16) u32 vcB[RPW][384];
    __shared__ float partA[RPW][CGC][9];
    __shared__ float partB[RPW][CGC][9];
    __shared__ int   toks[4][SEQL];
    __shared__ float yred[8];

    const int tid  = threadIdx.x;
    const int wg   = blockIdx.x;
    const int pr   = wg >> 3;            // ring-pair 0..31
    const int cg   = wg & 7;
    const int ringA = 2 * pr;
    const int wv   = tid >> 6;
    const int lane = tid & 63;
    const int gc   = cg * CGC + lane;
    const int row0 = pr * 4;

    for (int i = tid; i < 4 * SEQL; i += THR)
        toks[i >> 9][i & 511] = tokens[(row0 + (i >> 9)) * SEQL + (i & 511)];
    for (int i = tid; i < RPW * 256; i += THR) {
        vcA[i >> 8][128 + (i & 255)] = 0u;
        vcB[i >> 8][128 + (i & 255)] = 0u;
    }

    u32 we[16], ws[32];
    #pragma unroll
    for (int i = 0; i < 16; ++i) we[i] = W16[(size_t)(wv * 16 + i) * NCOL + gc];
    #pragma unroll
    for (int j = 0; j < 32; ++j) ws[j] = W16[(size_t)(128 + wv * 32 + j) * NCOL + gc];

    __syncthreads();

    const int er = tid >> 7, ee = tid & 127;   // emb role: global row er, pair ee
    {
        int tok = toks[er][0];
        float2 ev = *(const float2*)&V[(size_t)tok * EMBD + 2 * ee];
        u32 dw = packh2(ev.x, ev.y);
        if (er < 2) vcA[er][ee] = dw; else vcB[er - 2][ee] = dw;
    }
    __syncthreads();

    const float bias_r = (tid < 256) ? bias[cg * CGC + (tid & 63)] : 0.f;
    const int  lrow = lane >> 5, lpair = lane & 31;
    const bool own  = (wv == cg);
    const int  ringsel = tid >> 7, rrow = (tid >> 6) & 1, rcol = tid & 63;

    for (int t = 0; t < SEQL; ++t) {
        // ---- speculative exchange loads (state(t-1), tag t, slot (t+1)&1) ----
        u64* XA = X + (((size_t)((t + 1) & 1) * NRING + ringA    ) * RPW + lrow) * 256 + wv * 32 + lpair;
        u64* XB = X + (((size_t)((t + 1) & 1) * NRING + ringA + 1) * RPW + lrow) * 256 + wv * 32 + lpair;
        u64 vA = 0, vB = 0;
        if (!own) {
            vA = __hip_atomic_load(XA, __ATOMIC_RELAXED, __HIP_MEMORY_SCOPE_AGENT);
            vB = __hip_atomic_load(XB, __ATOMIC_RELAXED, __HIP_MEMORY_SCOPE_AGENT);
        }

        // emb(t+1) global prefetch
        const int tn   = (t + 1 < SEQL) ? (t + 1) : (SEQL - 1);
        const int tokn = toks[er][tn];
        const float2 ev = *(const float2*)&V[(size_t)tokn * EMBD + 2 * ee];

        // ---- E phase: emb part for both rings (hides load latency) ----
        float a0 = 0.f, a1 = 0.f, b0 = 0.f, b1 = 0.f;
        {
            const uint4* pa0 = (const uint4*)&vcA[0][wv * 16];
            const uint4* pa1 = (const uint4*)&vcA[1][wv * 16];
            const uint4* pb0 = (const uint4*)&vcB[0][wv * 16];
            const uint4* pb1 = (const uint4*)&vcB[1][wv * 16];
            #pragma unroll
            for (int j = 0; j < 4; ++j) {
                uint4 xa0 = pa0[j], xa1 = pa1[j], xb0 = pb0[j], xb1 = pb1[j];
                a0 = dot2(xa0.x, we[4*j+0], a0); a0 = dot2(xa0.y, we[4*j+1], a0);
                a0 = dot2(xa0.z, we[4*j+2], a0); a0 = dot2(xa0.w, we[4*j+3], a0);
                a1 = dot2(xa1.x, we[4*j+0], a1); a1 = dot2(xa1.y, we[4*j+1], a1);
                a1 = dot2(xa1.z, we[4*j+2], a1); a1 = dot2(xa1.w, we[4*j+3], a1);
                b0 = dot2(xb0.x, we[4*j+0], b0); b0 = dot2(xb0.y, we[4*j+1], b0);
                b0 = dot2(xb0.z, we[4*j+2], b0); b0 = dot2(xb0.w, we[4*j+3], b0);
                b1 = dot2(xb1.x, we[4*j+0], b1); b1 = dot2(xb1.y, we[4*j+1], b1);
                b1 = dot2(xb1.z, we[4*j+2], b1); b1 = dot2(xb1.w, we[4*j+3], b1);
            }
        }

        // ---- validate + publish slice A to LDS ----
        if (!own) {
            if (!__all((u32)(vA >> 32) == (u32)t)) {
                do {
                    __builtin_amdgcn_s_sleep(1);
                    vA = __hip_atomic_load(XA, __ATOMIC_RELAXED, __HIP_MEMORY_SCOPE_AGENT);
                } while (!__all((u32)(vA >> 32) == (u32)t));
            }
            vcA[lrow][128 + wv * 32 + lpair] = (u32)vA;
        }
        // ---- S_A: state part, ring A ----
        {
            const uint4* p0 = (const uint4*)&vcA[0][128 + wv * 32];
            const uint4* p1 = (const uint4*)&vcA[1][128 + wv * 32];
            #pragma unroll
            for (int j = 0; j < 8; ++j) {
                uint4 x0 = p0[j], x1 = p1[j];
                a0 = dot2(x0.x, ws[4*j+0], a0); a0 = dot2(x0.y, ws[4*j+1], a0);
                a0 = dot2(x0.z, ws[4*j+2], a0); a0 = dot2(x0.w, ws[4*j+3], a0);
                a1 = dot2(x1.x, ws[4*j+0], a1); a1 = dot2(x1.y, ws[4*j+1], a1);
                a1 = dot2(x1.z, ws[4*j+2], a1); a1 = dot2(x1.w, ws[4*j+3], a1);
            }
        }
        partA[0][lane][wv] = a0;
        partA[1][lane][wv] = a1;

        // ---- validate + publish slice B to LDS ----
        if (!own) {
            if (!__all((u32)(vB >> 32) == (u32)t)) {
                do {
                    __builtin_amdgcn_s_sleep(1);
                    vB = __hip_atomic_load(XB, __ATOMIC_RELAXED, __HIP_MEMORY_SCOPE_AGENT);
                } while (!__all((u32)(vB >> 32) == (u32)t));
            }
            vcB[lrow][128 + wv * 32 + lpair] = (u32)vB;
        }
        // ---- S_B: state part, ring B ----
        {
            const uint4* p0 = (const uint4*)&vcB[0][128 + wv * 32];
            const uint4* p1 = (const uint4*)&vcB[1][128 + wv * 32];
            #pragma unroll
            for (int j = 0; j < 8; ++j) {
                uint4 x0 = p0[j], x1 = p1[j];
                b0 = dot2(x0.x, ws[4*j+0], b0); b0 = dot2(x0.y, ws[4*j+1], b0);
                b0 = dot2(x0.z, ws[4*j+2], b0); b0 = dot2(x0.w, ws[4*j+3], b0);
                b1 = dot2(x1.x, ws[4*j+0], b1); b1 = dot2(x1.y, ws[4*j+1], b1);
                b1 = dot2(x1.z, ws[4*j+2], b1); b1 = dot2(x1.w, ws[4*j+3], b1);
            }
        }
        partB[0][lane][wv] = b0;
        partB[1][lane][wv] = b1;

        __syncthreads();   // B1: partials visible; all vc reads of step t done

        // ---- reduce + tanh + publish (tagged) ----
        if (tid < 256) {
            const float* P = ringsel ? &partB[rrow][rcol][0] : &partA[rrow][rcol][0];
            float s = P[0] + P[1] + P[2] + P[3] + P[4] + P[5] + P[6] + P[7] + bias_r;
            s = tanhf(s);
            float snb = __shfl_down(s, 1);
            if ((rcol & 1) == 0) {
                const int gp = cg * 32 + (rcol >> 1);
                u32 dw = packh2(s, snb);
                if (ringsel == 0) vcA[rrow][128 + gp] = dw;
                else              vcB[rrow][128 + gp] = dw;
                u64 pk = (u64)dw | ((u64)(u32)(t + 1) << 32);
                u64* dst = X + (((size_t)(t & 1) * NRING + ringA + ringsel) * RPW + rrow) * 256 + gp;
                __hip_atomic_store(dst, pk, __ATOMIC_RELAXED, __HIP_MEMORY_SCOPE_AGENT);
            }
        }
        {   // emb(t+1) -> LDS
            u32 dw = packh2(ev.x, ev.y);
            if (er < 2) vcA[er][ee] = dw; else vcB[er - 2][ee] = dw;
        }
        __syncthreads();   // B2
    }

    // ---- epilogue: cg==0 gathers state(511) (tag SEQL, slot 1) and computes y ----
    if (cg == 0) {
        if (wv != 0) {
            u64* XA = X + (((size_t)((SEQL - 1) & 1) * NRING + ringA    ) * RPW + lrow) * 256 + wv * 32 + lpair;
            u64* XB = X + (((size_t)((SEQL - 1) & 1) * NRING + ringA + 1) * RPW + lrow) * 256 + wv * 32 + lpair;
            u64 vA, vB;
            do {
                vA = __hip_atomic_load(XA, __ATOMIC_RELAXED, __HIP_MEMORY_SCOPE_AGENT);
            } while (!__all((u32)(vA >> 32) == (u32)SEQL));
            do {
                vB = __hip_atomic_load(XB, __ATOMIC_RELAXED, __HIP_MEMORY_SCOPE_AGENT);
            } while (!__all((u32)(vB >> 32) == (u32)SEQL));
            vcA[lrow][128 + wv * 32 + lpair] = (u32)vA;
            vcB[lrow][128 + wv * 32 + lpair] = (u32)vB;
        }
        __syncthreads();
        const int r = tid >> 7, q = tid & 127;
        u32 dA, dB;
        if (r < 2) { dA = vcA[r][128 + 2 * q];     dB = vcA[r][128 + 2 * q + 1]; }
        else       { dA = vcB[r - 2][128 + 2 * q]; dB = vcB[r - 2][128 + 2 * q + 1]; }
        h2 ha = __builtin_bit_cast(h2, dA), hb = __builtin_bit_cast(h2, dB);
        float p = (float)ha.x * Wd[4 * q + 0] + (float)ha.y * Wd[4 * q + 1]
                + (float)hb.x * Wd[4 * q + 2] + (float)hb.y * Wd[4 * q + 3];
        #pragma unroll
        for (int off = 32; off > 0; off >>= 1) p += __shfl_down(p, off);
        if ((tid & 63) == 0) yred[tid >> 6] = p;
        __syncthreads();
        if (tid < 4) y[row0 + tid] = yred[2 * tid] + yred[2 * tid + 1] + bd[0];
    }
}

extern "C" void kernel_launch(void* const* d_in, const int* in_sizes, int n_in,
                              void* d_out, int out_size, void* d_ws, size_t ws_size,
                              hipStream_t stream)
{
    const int*   tokens = (const int*)  d_in[0];
    const float* V      = (const float*)d_in[1];
    const float* W      = (const float*)d_in[2];
    const float* b      = (const float*)d_in[3];
    const float* Wd     = (const float*)d_in[4];
    const float* bd     = (const float*)d_in[5];
    float* y = (float*)d_out;

    u32* W16 = (u32*)((char*)d_ws + WS_W16_OFF);
    u64* X   = (u64*)((char*)d_ws + WS_X_OFF);

    hipLaunchKernelGGL(init_X, dim3(64), dim3(1024), 0, stream, X);
    hipLaunchKernelGGL(convert_W, dim3((384 * NCOL + 255) / 256), dim3(256), 0, stream, W, W16);
    hipLaunchKernelGGL(rnn_ring, dim3(256), dim3(THR), 0, stream,
                       tokens, V, W16, b, Wd, bd, y, X);
}